// Round 1
// 614.104 us; speedup vs baseline: 1.0417x; 1.0417x over previous
//
#include <hip/hip_runtime.h>
#include <stdint.h>

// x[B,V,I] fp32, group_index[V] int, weight[G,O,I] fp32, bias[G,O] fp32 -> out[B,V,O] fp32
#define B_DIM 128
#define V_DIM 1024
#define I_DIM 512
#define O_DIM 512
#define G_DIM 16

#define TM 128
#define TN 128
#define BK 32
#define KSTEPS (I_DIM / BK)   // 16
#define NTILES (O_DIM / TN)   // 4
#define NXCD 8

typedef __bf16 bf16x8 __attribute__((ext_vector_type(8)));
typedef __bf16 bf16x4 __attribute__((ext_vector_type(4)));
typedef float  f32x4  __attribute__((ext_vector_type(4)));

#define GLOBAL_AS __attribute__((address_space(1)))
#define LDS_AS    __attribute__((address_space(3)))

// async global->LDS DMA, 16B per lane; LDS dest = uniform base + lane*16 (HW rule)
__device__ __forceinline__ void dma16(const void* g, void* l) {
    __builtin_amdgcn_global_load_lds((const GLOBAL_AS uint32_t*)g,
                                     (LDS_AS uint32_t*)l, 16, 0, 0);
}

__device__ __forceinline__ bf16x8 cvt8(f32x4 lo, f32x4 hi) {
    bf16x8 r;
    r[0] = (__bf16)lo[0]; r[1] = (__bf16)lo[1]; r[2] = (__bf16)lo[2]; r[3] = (__bf16)lo[3];
    r[4] = (__bf16)hi[0]; r[5] = (__bf16)hi[1]; r[6] = (__bf16)hi[2]; r[7] = (__bf16)hi[3];
    return r;
}

// ---------------- pre-pass: W fp32 -> bf16 (into d_ws) ----------------
__global__ __launch_bounds__(256) void convert_w(const float* __restrict__ src,
                                                 __bf16* __restrict__ dst) {
    const int i = blockIdx.x * 256 + threadIdx.x;       // one float4 per thread
    float4 v = ((const float4*)src)[i];
    bf16x4 o;
    o[0] = (__bf16)v.x; o[1] = (__bf16)v.y; o[2] = (__bf16)v.z; o[3] = (__bf16)v.w;
    *(bf16x4*)&dst[(size_t)i * 4] = o;
}

// ---------------- main GEMM: per (v, n-tile) block, M=128 N=128 K=512 ----------------
// LDS (40 KB): A fp32 double-buffered (2x16KB, XOR-swizzled chunks), B bf16 single-buffered (8KB).
// A swizzle: row r (128B = 8 chunks of 16B), logical chunk c stored at slot c ^ (r&7).
// B swizzle: row r (64B = 4 chunks of 16B),  logical chunk c stored at slot c ^ ((r>>1)&3).
// Both make every ds_read_b128 phase <=2-way bank aliased (free).
//
// Block swizzle (NEW this round): the 4 n-tile blocks of one v share the same
// 256 KB A-tile x[:,v,:]. Default round-robin dispatch puts consecutive ids on
// DIFFERENT XCDs -> 4x HBM refetch of x (per-XCD L2s not shared). Remap so all
// 4 n-tiles of a v land on the SAME XCD (id % 8), consecutively:
//   xcd = id & 7; slot = id >> 3; v = (slot >> 2) * 8 + xcd; n = slot & 3.
// Bijective: 4096 blocks, V=1024 divisible by 8.
__global__ __launch_bounds__(256, 4)
void glinear_mfma(const float* __restrict__ x,
                  const int*   __restrict__ gidx,
                  const __bf16* __restrict__ wb,
                  const float* __restrict__ bias,
                  float*       __restrict__ out) {
    const int id   = blockIdx.x;
    const int xcd  = id & (NXCD - 1);
    const int slot = id >> 3;
    const int v    = (slot >> 2) * NXCD + xcd;
    const int n0   = (slot & (NTILES - 1)) * TN;
    const int g    = gidx[v];

    __shared__ float  lds_a[2][TM * BK];   // 2 x 16 KB
    __shared__ __bf16 lds_b[TN * BK];      // 8 KB

    const int tid  = threadIdx.x;
    const int lane = tid & 63;
    const int wave = tid >> 6;
    const int wm   = (wave & 1) * 64;
    const int wn   = (wave >> 1) * 64;
    const int fr   = lane & 15;
    const int c0   = lane >> 4;            // 0..3

    // ---- DMA descriptors ----
    // A: 16 x 1KB instrs (8 rows x 128B each); wave handles 4. lane -> row +(lane>>3), chunk (lane&7)^(lane>>3)
    const int ar = lane >> 3;
    const int agc = (lane & 7) ^ ar;
    const float* aga[4];
#pragma unroll
    for (int j = 0; j < 4; ++j) {
        const int r = wave * 32 + j * 8 + ar;
        aga[j] = x + ((size_t)r * V_DIM + v) * I_DIM + agc * 4;
    }
    // B: 8 x 1KB instrs (16 rows x 64B each); wave handles 2. lane -> row +(lane>>2), chunk (lane&3)^((lane>>3)&3)
    const int br = lane >> 2;
    const int bgc = (lane & 3) ^ ((lane >> 3) & 3);
    const __bf16* bga[2];
#pragma unroll
    for (int j = 0; j < 2; ++j) {
        const int r = wave * 32 + j * 16 + br;
        bga[j] = wb + ((size_t)(g * O_DIM + n0 + r)) * I_DIM + bgc * 8;
    }

    f32x4 acc[4][4];
    const f32x4 zero = {0.f, 0.f, 0.f, 0.f};
#pragma unroll
    for (int ms = 0; ms < 4; ++ms)
#pragma unroll
        for (int ns = 0; ns < 4; ++ns) acc[ms][ns] = zero;

    // prologue: stage kt=0
#pragma unroll
    for (int j = 0; j < 4; ++j)
        dma16(aga[j], &lds_a[0][(wave * 32 + j * 8) * BK]);
#pragma unroll
    for (int j = 0; j < 2; ++j)
        dma16(bga[j], &lds_b[(wave * 32 + j * 16) * BK]);
    __syncthreads();   // drains vmcnt -> DMA complete

    // frag-read swizzle slots (row bits reduce to fr bits; wm/wn/t*16 contribute 0)
    const int ar7 = fr & 7;
    const int as0 = (2 * c0)     ^ ar7;
    const int as1 = (2 * c0 + 1) ^ ar7;
    const int bs  = c0 ^ ((fr >> 1) & 3);

    for (int kt = 0; kt < KSTEPS; ++kt) {
        const int cur = kt & 1;

        bf16x8 av[4], bv[4];
#pragma unroll
        for (int t = 0; t < 4; ++t) {
            const float* ab = &lds_a[cur][(wm + t * 16 + fr) * BK];
            f32x4 alo = *(const f32x4*)(ab + as0 * 4);
            f32x4 ahi = *(const f32x4*)(ab + as1 * 4);
            av[t] = cvt8(alo, ahi);
            bv[t] = *(const bf16x8*)&lds_b[(wn + t * 16 + fr) * BK + bs * 8];
        }
        __syncthreads();   // all waves finished reading lds_b / lds_a[cur]

        if (kt < KSTEPS - 1) {
#pragma unroll
            for (int j = 0; j < 4; ++j)
                dma16(aga[j] + (kt + 1) * BK, &lds_a[cur ^ 1][(wave * 32 + j * 8) * BK]);
#pragma unroll
            for (int j = 0; j < 2; ++j)
                dma16(bga[j] + (kt + 1) * BK, &lds_b[(wave * 32 + j * 16) * BK]);
        }

#pragma unroll
        for (int ms = 0; ms < 4; ++ms)
#pragma unroll
            for (int ns = 0; ns < 4; ++ns)
                acc[ms][ns] = __builtin_amdgcn_mfma_f32_16x16x32_bf16(
                    av[ms], bv[ns], acc[ms][ns], 0, 0, 0);

        __syncthreads();   // drains vmcnt -> next tile resident
    }

    // epilogue: C/D layout col=lane&15, row=(lane>>4)*4+reg (verified round 1)
    const float* bptr = bias + (size_t)g * O_DIM + n0;
    float bvals[4];
#pragma unroll
    for (int ns = 0; ns < 4; ++ns) bvals[ns] = bptr[wn + ns * 16 + fr];

    const int rbase = (lane >> 4) * 4;
#pragma unroll
    for (int ms = 0; ms < 4; ++ms) {
#pragma unroll
        for (int r = 0; r < 4; ++r) {
            const int m = wm + ms * 16 + rbase + r;
            float* orow = out + ((size_t)m * V_DIM + v) * O_DIM + n0;
#pragma unroll
            for (int ns = 0; ns < 4; ++ns)
                orow[wn + ns * 16 + fr] = acc[ms][ns][r] + bvals[ns];
        }
    }
}

// ---------------- fallback (round-1 kernel) if ws too small ----------------
#define LDK 40
__device__ __forceinline__ __bf16 f2bf(float f) {
    unsigned u = __builtin_bit_cast(unsigned, f);
    u += 0x7fffu + ((u >> 16) & 1u);
    unsigned short h = (unsigned short)(u >> 16);
    return __builtin_bit_cast(__bf16, h);
}
__device__ __forceinline__ void cvt_store16(__bf16* dst, const float4* src) {
    bf16x8 lo, hi;
    lo[0] = f2bf(src[0].x); lo[1] = f2bf(src[0].y); lo[2] = f2bf(src[0].z); lo[3] = f2bf(src[0].w);
    lo[4] = f2bf(src[1].x); lo[5] = f2bf(src[1].y); lo[6] = f2bf(src[1].z); lo[7] = f2bf(src[1].w);
    hi[0] = f2bf(src[2].x); hi[1] = f2bf(src[2].y); hi[2] = f2bf(src[2].z); hi[3] = f2bf(src[2].w);
    hi[4] = f2bf(src[3].x); hi[5] = f2bf(src[3].y); hi[6] = f2bf(src[3].z); hi[7] = f2bf(src[3].w);
    *(bf16x8*)dst = lo; *(bf16x8*)(dst + 8) = hi;
}
__global__ __launch_bounds__(256, 2)
void glinear_fb(const float* __restrict__ x, const int* __restrict__ gidx,
                const float* __restrict__ w, const float* __restrict__ bias,
                float* __restrict__ out) {
    const int v = blockIdx.y, n0 = blockIdx.x * TN, g = gidx[v];
    __shared__ __bf16 lds_a[2][TM * LDK];
    __shared__ __bf16 lds_b[2][TN * LDK];
    const int tid = threadIdx.x, lane = tid & 63, wave = tid >> 6;
    const int wm = (wave & 1) * 64, wn = (wave >> 1) * 64;
    const int fr = lane & 15, kg = (lane >> 4) * 8;
    const int srow = tid >> 1, skh = (tid & 1) * 16;
    const float* xrow = x + ((size_t)srow * V_DIM + v) * I_DIM + skh;
    const float* wrow = w + (((size_t)g * O_DIM) + n0 + srow) * I_DIM + skh;
    const int soff = srow * LDK + skh;
    f32x4 acc[4][4];
    const f32x4 zero = {0.f, 0.f, 0.f, 0.f};
#pragma unroll
    for (int ms = 0; ms < 4; ++ms)
#pragma unroll
        for (int ns = 0; ns < 4; ++ns) acc[ms][ns] = zero;
    {
        float4 ax[4], bx[4];
#pragma unroll
        for (int i = 0; i < 4; ++i) { ax[i] = ((const float4*)xrow)[i]; bx[i] = ((const float4*)wrow)[i]; }
        cvt_store16(&lds_a[0][soff], ax); cvt_store16(&lds_b[0][soff], bx);
    }
    __syncthreads();
    for (int kt = 0; kt < KSTEPS; ++kt) {
        const int cur = kt & 1, nxt = cur ^ 1;
        float4 ax[4], bx[4];
        if (kt < KSTEPS - 1) {
            const float* xp = xrow + (kt + 1) * BK;
            const float* wp = wrow + (kt + 1) * BK;
#pragma unroll
            for (int i = 0; i < 4; ++i) { ax[i] = ((const float4*)xp)[i]; bx[i] = ((const float4*)wp)[i]; }
        }
        bf16x8 av[4], bv[4];
#pragma unroll
        for (int t = 0; t < 4; ++t) {
            av[t] = *(const bf16x8*)&lds_a[cur][(wm + t * 16 + fr) * LDK + kg];
            bv[t] = *(const bf16x8*)&lds_b[cur][(wn + t * 16 + fr) * LDK + kg];
        }
#pragma unroll
        for (int ms = 0; ms < 4; ++ms)
#pragma unroll
            for (int ns = 0; ns < 4; ++ns)
                acc[ms][ns] = __builtin_amdgcn_mfma_f32_16x16x32_bf16(av[ms], bv[ns], acc[ms][ns], 0, 0, 0);
        if (kt < KSTEPS - 1) { cvt_store16(&lds_a[nxt][soff], ax); cvt_store16(&lds_b[nxt][soff], bx); }
        __syncthreads();
    }
    const float* bptr = bias + (size_t)g * O_DIM + n0;
    float bvals[4];
#pragma unroll
    for (int ns = 0; ns < 4; ++ns) bvals[ns] = bptr[wn + ns * 16 + fr];
    const int rbase = (lane >> 4) * 4;
#pragma unroll
    for (int ms = 0; ms < 4; ++ms)
#pragma unroll
        for (int r = 0; r < 4; ++r) {
            const int m = wm + ms * 16 + rbase + r;
            float* orow = out + ((size_t)m * V_DIM + v) * O_DIM + n0;
#pragma unroll
            for (int ns = 0; ns < 4; ++ns) orow[wn + ns * 16 + fr] = acc[ms][ns][r] + bvals[ns];
        }
}

extern "C" void kernel_launch(void* const* d_in, const int* in_sizes, int n_in,
                              void* d_out, int out_size, void* d_ws, size_t ws_size,
                              hipStream_t stream) {
    const float* x    = (const float*)d_in[0];
    const int*   gidx = (const int*)d_in[1];
    const float* w    = (const float*)d_in[2];
    const float* bias = (const float*)d_in[3];
    float*       out  = (float*)d_out;

    const size_t w_elems = (size_t)G_DIM * O_DIM * I_DIM;      // 4,194,304
    const size_t need    = w_elems * sizeof(__bf16);           // 8 MB

    if (ws_size >= need) {
        __bf16* wb = (__bf16*)d_ws;
        convert_w<<<(int)(w_elems / 4 / 256), 256, 0, stream>>>(w, wb);
        glinear_mfma<<<dim3(NTILES * V_DIM), 256, 0, stream>>>(x, gidx, wb, bias, out);
    } else {
        dim3 grid(O_DIM / TN, V_DIM);
        glinear_fb<<<grid, 256, 0, stream>>>(x, gidx, w, bias, out);
    }
}

// Round 2
// 536.006 us; speedup vs baseline: 1.1935x; 1.1457x over previous
//
#include <hip/hip_runtime.h>
#include <stdint.h>

// x[B,V,I] fp32, group_index[V] int, weight[G,O,I] fp32, bias[G,O] fp32 -> out[B,V,O] fp32
#define B_DIM 128
#define V_DIM 1024
#define I_DIM 512
#define O_DIM 512
#define G_DIM 16

#define TM 128
#define TN 512                       // full N per block: A staged ONCE per v
#define BK 32
#define KSTEPS (I_DIM / BK)          // 16
#define TILE_ELEMS (O_DIM * BK)      // 16384 bf16 per packed (g,kt) B-tile

typedef __bf16 bf16x8 __attribute__((ext_vector_type(8)));
typedef __bf16 bf16x4 __attribute__((ext_vector_type(4)));
typedef float  f32x4  __attribute__((ext_vector_type(4)));

#define GLOBAL_AS __attribute__((address_space(1)))
#define LDS_AS    __attribute__((address_space(3)))

// async global->LDS DMA, 16B per lane; LDS dest = uniform base + lane*16 (HW rule)
__device__ __forceinline__ void dma16(const void* g, void* l) {
    __builtin_amdgcn_global_load_lds((const GLOBAL_AS uint32_t*)g,
                                     (LDS_AS uint32_t*)l, 16, 0, 0);
}

__device__ __forceinline__ bf16x8 cvt8(f32x4 lo, f32x4 hi) {
    bf16x8 r;
    r[0] = (__bf16)lo[0]; r[1] = (__bf16)lo[1]; r[2] = (__bf16)lo[2]; r[3] = (__bf16)lo[3];
    r[4] = (__bf16)hi[0]; r[5] = (__bf16)hi[1]; r[6] = (__bf16)hi[2]; r[7] = (__bf16)hi[3];
    return r;
}

// ---------------- pre-pass: W fp32 -> packed bf16 tiles (into d_ws) ----------------
// Layout: wp[g][kt][o][slot][8], slot = chunk ^ ((o>>1)&3)  (chunk = 16B = 8 bf16).
// Each (g,kt) tile is 32 KB contiguous; main kernel DMAs it with linear lane*16B
// addresses (contiguous fast path) and the LDS lands pre-swizzled for conflict-free
// ds_read_b128 (same swizzle scheme round 1 verified).
__global__ __launch_bounds__(256) void convert_w_packed(const float* __restrict__ src,
                                                        __bf16* __restrict__ dst) {
    const int cid  = blockIdx.x * 256 + threadIdx.x;    // one 16B chunk
    const int c    = cid & 63;                          // chunk within row (64 = 512/8)
    const int olin = cid >> 6;                          // g*512 + o
    const int o    = olin & (O_DIM - 1);
    const int g    = olin >> 9;
    const int kt   = c >> 2;                            // which K-tile
    const int cc   = c & 3;                             // chunk within K-tile row
    const int s    = cc ^ ((o >> 1) & 3);               // pre-applied LDS swizzle
    const float4* sp = (const float4*)(src + (size_t)olin * I_DIM + c * 8);
    float4 v0 = sp[0], v1 = sp[1];
    bf16x8 r;
    r[0] = (__bf16)v0.x; r[1] = (__bf16)v0.y; r[2] = (__bf16)v0.z; r[3] = (__bf16)v0.w;
    r[4] = (__bf16)v1.x; r[5] = (__bf16)v1.y; r[6] = (__bf16)v1.z; r[7] = (__bf16)v1.w;
    *(bf16x8*)&dst[((size_t)(g * KSTEPS + kt) * O_DIM + o) * BK + s * 8] = r;
}

// ---------------- main GEMM: one block per v, M=128 N=512 K=512, 8 waves ----------------
// LDS 48 KB: A fp32 single-buffered 16 KB (XOR-swizzled 16B chunks, slot = c ^ (r&7)),
// B bf16 single-buffered 32 KB (pre-swizzled by convert_w_packed).
// Single-buffer is safe: all fragments are read into registers BEFORE the barrier that
// releases the buffers for the next tile's DMA (round-1-verified pattern).
// Per wave-step: 2 A-DMA (scattered 128B rows) + 4 B-DMA (contiguous 1KB) + 32 MFMA.
__global__ __launch_bounds__(512, 2)
void glinear_mfma(const float* __restrict__ x,
                  const int*   __restrict__ gidx,
                  const __bf16* __restrict__ wb,
                  const float* __restrict__ bias,
                  float*       __restrict__ out) {
    const int v = blockIdx.x;
    const int g = gidx[v];

    __shared__ float  lds_a[TM * BK];   // 16 KB
    __shared__ __bf16 lds_b[TN * BK];   // 32 KB

    const int tid  = threadIdx.x;
    const int lane = tid & 63;
    const int wave = tid >> 6;          // 0..7
    const int wm   = (wave & 1) * 64;
    const int wn   = (wave >> 1) * 128;
    const int fr   = lane & 15;
    const int c0   = lane >> 4;         // 0..3

    // ---- A DMA descriptors: 2 instrs/wave, 8 rows x 128B each, chunk-swizzled ----
    const int ar  = lane >> 3;
    const int agc = (lane & 7) ^ ar;
    const float* aga[2];
#pragma unroll
    for (int j = 0; j < 2; ++j) {
        const int r = wave * 16 + j * 8 + ar;
        aga[j] = x + ((size_t)r * V_DIM + v) * I_DIM + agc * 4;
    }
    // ---- B DMA: 4 instrs/wave, fully contiguous from packed tiles ----
    const __bf16* btile = wb + (size_t)g * KSTEPS * TILE_ELEMS;

    f32x4 acc[4][8];
    const f32x4 zero = {0.f, 0.f, 0.f, 0.f};
#pragma unroll
    for (int ms = 0; ms < 4; ++ms)
#pragma unroll
        for (int ns = 0; ns < 8; ++ns) acc[ms][ns] = zero;

    // prologue: stage kt=0
#pragma unroll
    for (int j = 0; j < 2; ++j)
        dma16(aga[j], &lds_a[(wave * 16 + j * 8) * BK]);
#pragma unroll
    for (int j = 0; j < 4; ++j)
        dma16(btile + (wave * 64 + j * 16) * BK + lane * 8,
              &lds_b[(wave * 64 + j * 16) * BK]);
    __syncthreads();   // drains vmcnt -> tile 0 resident

    // frag-read swizzle slots (row bits reduce to fr bits)
    const int ar7 = fr & 7;
    const int as0 = (2 * c0)     ^ ar7;
    const int as1 = (2 * c0 + 1) ^ ar7;
    const int bs  = c0 ^ ((fr >> 1) & 3);

    for (int kt = 0; kt < KSTEPS; ++kt) {
        bf16x8 av[4], bv[8];
#pragma unroll
        for (int t = 0; t < 4; ++t) {
            const float* ab = &lds_a[(wm + t * 16 + fr) * BK];
            f32x4 alo = *(const f32x4*)(ab + as0 * 4);
            f32x4 ahi = *(const f32x4*)(ab + as1 * 4);
            av[t] = cvt8(alo, ahi);
        }
#pragma unroll
        for (int t = 0; t < 8; ++t)
            bv[t] = *(const bf16x8*)&lds_b[(wn + t * 16 + fr) * BK + bs * 8];
        __syncthreads();   // all waves have their frags in regs -> buffers free

        if (kt < KSTEPS - 1) {
#pragma unroll
            for (int j = 0; j < 2; ++j)
                dma16(aga[j] + (kt + 1) * BK, &lds_a[(wave * 16 + j * 8) * BK]);
            const __bf16* bt = btile + (size_t)(kt + 1) * TILE_ELEMS;
#pragma unroll
            for (int j = 0; j < 4; ++j)
                dma16(bt + (wave * 64 + j * 16) * BK + lane * 8,
                      &lds_b[(wave * 64 + j * 16) * BK]);
        }

#pragma unroll
        for (int ms = 0; ms < 4; ++ms)
#pragma unroll
            for (int ns = 0; ns < 8; ++ns)
                acc[ms][ns] = __builtin_amdgcn_mfma_f32_16x16x32_bf16(
                    av[ms], bv[ns], acc[ms][ns], 0, 0, 0);

        if (kt < KSTEPS - 1)
            __syncthreads();   // drains vmcnt -> next tile resident
    }

    // epilogue: C/D layout col=lane&15, row=(lane>>4)*4+reg (verified round 1)
    const float* bptr = bias + (size_t)g * O_DIM;
    float bvals[8];
#pragma unroll
    for (int ns = 0; ns < 8; ++ns) bvals[ns] = bptr[wn + ns * 16 + fr];

    const int rbase = (lane >> 4) * 4;
#pragma unroll
    for (int ms = 0; ms < 4; ++ms) {
#pragma unroll
        for (int r = 0; r < 4; ++r) {
            const int m = wm + ms * 16 + rbase + r;
            float* orow = out + ((size_t)m * V_DIM + v) * O_DIM;
#pragma unroll
            for (int ns = 0; ns < 8; ++ns)
                orow[wn + ns * 16 + fr] = acc[ms][ns][r] + bvals[ns];
        }
    }
}

// ---------------- fallback (round-1 kernel) if ws too small ----------------
#define FBTN 128
#define LDK 40
__device__ __forceinline__ __bf16 f2bf(float f) {
    unsigned u = __builtin_bit_cast(unsigned, f);
    u += 0x7fffu + ((u >> 16) & 1u);
    unsigned short h = (unsigned short)(u >> 16);
    return __builtin_bit_cast(__bf16, h);
}
__device__ __forceinline__ void cvt_store16(__bf16* dst, const float4* src) {
    bf16x8 lo, hi;
    lo[0] = f2bf(src[0].x); lo[1] = f2bf(src[0].y); lo[2] = f2bf(src[0].z); lo[3] = f2bf(src[0].w);
    lo[4] = f2bf(src[1].x); lo[5] = f2bf(src[1].y); lo[6] = f2bf(src[1].z); lo[7] = f2bf(src[1].w);
    hi[0] = f2bf(src[2].x); hi[1] = f2bf(src[2].y); hi[2] = f2bf(src[2].z); hi[3] = f2bf(src[2].w);
    hi[4] = f2bf(src[3].x); hi[5] = f2bf(src[3].y); hi[6] = f2bf(src[3].z); hi[7] = f2bf(src[3].w);
    *(bf16x8*)dst = lo; *(bf16x8*)(dst + 8) = hi;
}
__global__ __launch_bounds__(256, 2)
void glinear_fb(const float* __restrict__ x, const int* __restrict__ gidx,
                const float* __restrict__ w, const float* __restrict__ bias,
                float* __restrict__ out) {
    const int v = blockIdx.y, n0 = blockIdx.x * FBTN, g = gidx[v];
    __shared__ __bf16 lds_a[2][TM * LDK];
    __shared__ __bf16 lds_b[2][FBTN * LDK];
    const int tid = threadIdx.x, lane = tid & 63, wave = tid >> 6;
    const int wm = (wave & 1) * 64, wn = (wave >> 1) * 64;
    const int fr = lane & 15, kg = (lane >> 4) * 8;
    const int srow = tid >> 1, skh = (tid & 1) * 16;
    const float* xrow = x + ((size_t)srow * V_DIM + v) * I_DIM + skh;
    const float* wrow = w + (((size_t)g * O_DIM) + n0 + srow) * I_DIM + skh;
    const int soff = srow * LDK + skh;
    f32x4 acc[4][4];
    const f32x4 zero = {0.f, 0.f, 0.f, 0.f};
#pragma unroll
    for (int ms = 0; ms < 4; ++ms)
#pragma unroll
        for (int ns = 0; ns < 4; ++ns) acc[ms][ns] = zero;
    {
        float4 ax[4], bx[4];
#pragma unroll
        for (int i = 0; i < 4; ++i) { ax[i] = ((const float4*)xrow)[i]; bx[i] = ((const float4*)wrow)[i]; }
        cvt_store16(&lds_a[0][soff], ax); cvt_store16(&lds_b[0][soff], bx);
    }
    __syncthreads();
    for (int kt = 0; kt < KSTEPS; ++kt) {
        const int cur = kt & 1, nxt = cur ^ 1;
        float4 ax[4], bx[4];
        if (kt < KSTEPS - 1) {
            const float* xp = xrow + (kt + 1) * BK;
            const float* wp = wrow + (kt + 1) * BK;
#pragma unroll
            for (int i = 0; i < 4; ++i) { ax[i] = ((const float4*)xp)[i]; bx[i] = ((const float4*)wp)[i]; }
        }
        bf16x8 av[4], bv[4];
#pragma unroll
        for (int t = 0; t < 4; ++t) {
            av[t] = *(const bf16x8*)&lds_a[cur][(wm + t * 16 + fr) * LDK + kg];
            bv[t] = *(const bf16x8*)&lds_b[cur][(wn + t * 16 + fr) * LDK + kg];
        }
#pragma unroll
        for (int ms = 0; ms < 4; ++ms)
#pragma unroll
            for (int ns = 0; ns < 4; ++ns)
                acc[ms][ns] = __builtin_amdgcn_mfma_f32_16x16x32_bf16(av[ms], bv[ns], acc[ms][ns], 0, 0, 0);
        if (kt < KSTEPS - 1) { cvt_store16(&lds_a[nxt][soff], ax); cvt_store16(&lds_b[nxt][soff], bx); }
        __syncthreads();
    }
    const float* bptr = bias + (size_t)g * O_DIM + n0;
    float bvals[4];
#pragma unroll
    for (int ns = 0; ns < 4; ++ns) bvals[ns] = bptr[wn + ns * 16 + fr];
    const int rbase = (lane >> 4) * 4;
#pragma unroll
    for (int ms = 0; ms < 4; ++ms)
#pragma unroll
        for (int r = 0; r < 4; ++r) {
            const int m = wm + ms * 16 + rbase + r;
            float* orow = out + ((size_t)m * V_DIM + v) * O_DIM + n0;
#pragma unroll
            for (int ns = 0; ns < 4; ++ns) orow[wn + ns * 16 + fr] = acc[ms][ns][r] + bvals[ns];
        }
}

extern "C" void kernel_launch(void* const* d_in, const int* in_sizes, int n_in,
                              void* d_out, int out_size, void* d_ws, size_t ws_size,
                              hipStream_t stream) {
    const float* x    = (const float*)d_in[0];
    const int*   gidx = (const int*)d_in[1];
    const float* w    = (const float*)d_in[2];
    const float* bias = (const float*)d_in[3];
    float*       out  = (float*)d_out;

    const size_t w_elems = (size_t)G_DIM * O_DIM * I_DIM;      // 4,194,304
    const size_t need    = w_elems * sizeof(__bf16);           // 8 MB

    if (ws_size >= need) {
        __bf16* wb = (__bf16*)d_ws;
        // one thread per 16B chunk: G*O*(I/8) = 524288 chunks -> 2048 blocks
        convert_w_packed<<<(int)(w_elems / 8 / 256), 256, 0, stream>>>(w, wb);
        glinear_mfma<<<dim3(V_DIM), 512, 0, stream>>>(x, gidx, wb, bias, out);
    } else {
        dim3 grid(O_DIM / FBTN, V_DIM);
        glinear_fb<<<grid, 256, 0, stream>>>(x, gidx, w, bias, out);
    }
}